// Round 1
// 991.258 us; speedup vs baseline: 1.1145x; 1.1145x over previous
//
#include <hip/hip_runtime.h>
#include <hip/hip_bf16.h>

#define B_ 2
#define S_ 2048
#define D_ 4096
#define NH_ 32
#define NKV_ 8
#define HD_ 128
#define M_ (B_ * S_)

typedef __bf16 bf16x8_t __attribute__((ext_vector_type(8)));
typedef float f32x4_t __attribute__((ext_vector_type(4)));

__device__ __forceinline__ void gload16(const __bf16* g, __bf16* l) {
  __builtin_amdgcn_global_load_lds(
      (const __attribute__((address_space(1))) void*)g,
      (__attribute__((address_space(3))) void*)l, 16, 0, 0);
}

// ---------------- fp32 -> bf16 converts ----------------
// x (16.7M) + wq (16.7M) + wk (4.2M) + wv (4.2M), 8 elts/thread
__global__ __launch_bounds__(256) void convert_main(const float* __restrict__ x,
                                                    const float* __restrict__ wq,
                                                    const float* __restrict__ wk,
                                                    const float* __restrict__ wv,
                                                    __bf16* __restrict__ xb,
                                                    __bf16* __restrict__ wqkv) {
  size_t c = (size_t)blockIdx.x * 256 + threadIdx.x;
  const float* src;
  __bf16* dst;
  if (c < 2097152) { src = x + c * 8; dst = xb + c * 8; }
  else if (c < 4194304) { c -= 2097152; src = wq + c * 8; dst = wqkv + c * 8; }
  else if (c < 4718592) { c -= 4194304; src = wk + c * 8; dst = wqkv + 16777216 + c * 8; }
  else { c -= 4718592; src = wv + c * 8; dst = wqkv + 20971520 + c * 8; }
  const float4* s4 = reinterpret_cast<const float4*>(src);
  float4 a = s4[0], b = s4[1];
  bf16x8_t t;
  t[0] = (__bf16)a.x; t[1] = (__bf16)a.y; t[2] = (__bf16)a.z; t[3] = (__bf16)a.w;
  t[4] = (__bf16)b.x; t[5] = (__bf16)b.y; t[6] = (__bf16)b.z; t[7] = (__bf16)b.w;
  *reinterpret_cast<bf16x8_t*>(dst) = t;
}

__global__ __launch_bounds__(256) void convert_wo(const float* __restrict__ wo,
                                                  __bf16* __restrict__ wob) {
  size_t c = (size_t)blockIdx.x * 256 + threadIdx.x;
  const float4* s4 = reinterpret_cast<const float4*>(wo + c * 8);
  float4 a = s4[0], b = s4[1];
  bf16x8_t t;
  t[0] = (__bf16)a.x; t[1] = (__bf16)a.y; t[2] = (__bf16)a.z; t[3] = (__bf16)a.w;
  t[4] = (__bf16)b.x; t[5] = (__bf16)b.y; t[6] = (__bf16)b.z; t[7] = (__bf16)b.w;
  *reinterpret_cast<bf16x8_t*>(wob + c * 8) = t;
}

// ---------------- GEMM (m97 structure): C = A[M][K] * Bm[N][K]^T ----------------
// 128x128 tile, BK=32, 4 waves 4x4 mfma_16x16x32_bf16, global_load_lds width 16
template <bool SPLIT, bool OUTF32>
__global__ __launch_bounds__(256) void gemm_bt(const __bf16* __restrict__ A,
                                               const __bf16* __restrict__ Bm,
                                               void* __restrict__ C0,
                                               void* __restrict__ C1,
                                               int N, int K) {
  __shared__ __attribute__((aligned(16))) __bf16 As[128 * 32];  // unpadded: global_load_lds order
  __shared__ __attribute__((aligned(16))) __bf16 Bs[128 * 32];
  const int tid = threadIdx.x;
  const int lane = tid & 63;
  const int w = tid >> 6;
  const int lo = lane & 15;
  const int hi = lane >> 4;
  const int wm = (w & 1) * 64;
  const int wn = (w >> 1) * 64;
  const int m0 = blockIdx.y * 128;
  const int n0 = blockIdx.x * 128;

  // staging: lane l covers row l>>2, 16B chunk l&3 -> LDS offset == lane*16 (HW order)
  const int srow = w * 32 + (lane >> 2);
  const int scol = (lane & 3) * 8;
  const __bf16* ga0 = A + (size_t)(m0 + srow) * K + scol;
  const __bf16* ga1 = A + (size_t)(m0 + srow + 16) * K + scol;
  const __bf16* gb0 = Bm + (size_t)(n0 + srow) * K + scol;
  const __bf16* gb1 = Bm + (size_t)(n0 + srow + 16) * K + scol;
  __bf16* la0 = &As[(w * 32) * 32];
  __bf16* la1 = &As[(w * 32 + 16) * 32];
  __bf16* lb0 = &Bs[(w * 32) * 32];
  __bf16* lb1 = &Bs[(w * 32 + 16) * 32];

  f32x4_t acc[4][4] = {};

  for (int k0 = 0; k0 < K; k0 += 32) {
    __syncthreads();
    gload16(ga0 + k0, la0);
    gload16(ga1 + k0, la1);
    gload16(gb0 + k0, lb0);
    gload16(gb1 + k0, lb1);
    __syncthreads();  // drains vmcnt before barrier -> LDS valid
    bf16x8_t af[4], bfr[4];
#pragma unroll
    for (int mi = 0; mi < 4; mi++)
      af[mi] = *reinterpret_cast<const bf16x8_t*>(&As[(wm + mi * 16 + lo) * 32 + hi * 8]);
#pragma unroll
    for (int ni = 0; ni < 4; ni++)
      bfr[ni] = *reinterpret_cast<const bf16x8_t*>(&Bs[(wn + ni * 16 + lo) * 32 + hi * 8]);
#pragma unroll
    for (int mi = 0; mi < 4; mi++)
#pragma unroll
      for (int ni = 0; ni < 4; ni++)
        acc[mi][ni] = __builtin_amdgcn_mfma_f32_16x16x32_bf16(af[mi], bfr[ni], acc[mi][ni], 0, 0, 0);
  }

  // epilogue: D layout col=lane&15, row=(lane>>4)*4+r
  __bf16* Cb = nullptr;
  float* Cf = nullptr;
  int ldc, nb;
  if constexpr (SPLIT) {
    if (n0 < 4096) { Cb = (__bf16*)C0; ldc = 4096; nb = n0; }
    else { Cb = (__bf16*)C1; ldc = 2048; nb = n0 - 4096; }
  } else {
    ldc = N; nb = n0;
    if constexpr (OUTF32) Cf = (float*)C0; else Cb = (__bf16*)C0;
  }
#pragma unroll
  for (int mi = 0; mi < 4; mi++) {
    const int mrow = m0 + wm + mi * 16 + hi * 4;
#pragma unroll
    for (int ni = 0; ni < 4; ni++) {
      const int ncol = nb + wn + ni * 16 + lo;
#pragma unroll
      for (int r = 0; r < 4; r++) {
        if constexpr (OUTF32)
          Cf[(size_t)(mrow + r) * ldc + ncol] = acc[mi][ni][r];
        else
          Cb[(size_t)(mrow + r) * ldc + ncol] = (__bf16)acc[mi][ni][r];
      }
    }
  }
}

// ---------------- RoPE (in-place; q: (M,NH,HD), kv: (M,2048) K at hkv*128) ----------------
typedef __bf16 bf16x2_t __attribute__((ext_vector_type(2)));
__global__ __launch_bounds__(256) void rope_kernel(__bf16* __restrict__ q,
                                                   __bf16* __restrict__ kv,
                                                   const float* __restrict__ fcos,
                                                   const float* __restrict__ fsin) {
  const int p = blockIdx.x * 256 + threadIdx.x;
  const int j = p & 63;
  int rem = p >> 6;
  const int hh = rem % (NH_ + NKV_);
  rem /= (NH_ + NKV_);
  const int s = rem % S_;
  const int b = rem / S_;
  const float c = fcos[s * 64 + j];
  const float sn = fsin[s * 64 + j];
  __bf16* base;
  if (hh < NH_)
    base = q + ((size_t)(b * S_ + s) * NH_ + hh) * HD_ + 2 * j;
  else
    base = kv + (size_t)(b * S_ + s) * 2048 + (hh - NH_) * HD_ + 2 * j;
  bf16x2_t xv = *reinterpret_cast<const bf16x2_t*>(base);
  const float xe = (float)xv[0], xo = (float)xv[1];
  bf16x2_t ov;
  ov[0] = (__bf16)(xe * c - xo * sn);
  ov[1] = (__bf16)(xe * sn + xo * c);
  *reinterpret_cast<bf16x2_t*>(base) = ov;
}

// ---------------- Flash attention ----------------
// R3 changes vs R2 baseline (423 us, MfmaUtil 7.3%, Occupancy 6.2%):
//  - PAIRED q-tiles: block handles qt=a then qt=15-a -> every block does exactly
//    34 key-tile iters; grid 512 blocks = one resident generation (2 blocks/CU,
//    VGPR~200 -> 2 waves/SIMD), no causal tail.
//  - one-ahead REGISTER PREFETCH of next K/V tile (T14): loads issued before the
//    compute phase; vmcnt wait lands at next iter's ds_write -> L2/L3 latency
//    hides under QK/softmax/PV.
//  - XCD-PINNING swizzle (T1): hkv = flat&7 so all blocks sharing a KV head-group
//    land on one XCD; per-XCD KV working set ~2MB < 4MiB L2 -> staging L2-hits.
//  - T5 setprio(1) around MFMA clusters (+4-7% attn, m191).
__global__ __launch_bounds__(256) void attn_kernel(const __bf16* __restrict__ q,
                                                   const __bf16* __restrict__ kv,
                                                   __bf16* __restrict__ o) {
  // grid (8, 32, 2) -> flat 0..511; round-robin XCD assumption: xcd = flat & 7
  const int flat = blockIdx.x + (blockIdx.y << 3) + (blockIdx.z << 8);
  const int hkv = flat & 7;               // pin KV head-group to one XCD
  const int idx = flat >> 3;              // 0..63
  const int h = hkv * 4 + ((idx >> 3) & 3);
  const int b = idx >> 5;
  const int xpair = idx & 7;              // pairs (xpair, 15-xpair)

  const int tid = threadIdx.x;
  const int lane = tid & 63;
  const int w = tid >> 6;
  const int lo = lane & 15;
  const int hi = lane >> 4;

  __shared__ __attribute__((aligned(16))) __bf16 Ks[64 * 132];   // [key][hd] pad 128->132
  __shared__ __attribute__((aligned(16))) __bf16 Vt[128 * 68];   // [hd][key] pad 64->68
  __shared__ __attribute__((aligned(16))) __bf16 Ps[4][32 * 68]; // per-wave P (32 rows)

  bf16x8_t ones;
#pragma unroll
  for (int e = 0; e < 8; e++) ones[e] = (__bf16)1.0f;

  constexpr float SC = 0.08838834764831845f * 1.44269504088896f;  // scale * log2(e)

  // staging index precompute (same decomposition as R2)
  const __bf16* kvb = kv + (size_t)b * S_ * 2048 + hkv * 128;
  int kkey[4], khc[4], vkey[4], vhc[4];
#pragma unroll
  for (int i = 0; i < 4; i++) {
    const int c = tid + i * 256;
    kkey[i] = c >> 4; khc[i] = c & 15;   // K: [64 keys][16 chunks]
    vkey[i] = c & 63; vhc[i] = c >> 6;   // V: [16 chunks][64 keys]
  }

  bf16x8_t kreg[4], vreg[4];

  for (int pass = 0; pass < 2; pass++) {
    const int qt = pass ? (15 - xpair) : xpair;  // light tile first (warms KV prefix)
    const int q0 = qt * 128;

    // Q fragments: wave w owns rows q0+w*32 .. +32 (2 m-frags)
    bf16x8_t qf[2][4];
#pragma unroll
    for (int mi = 0; mi < 2; mi++) {
      const size_t qbase = ((size_t)(b * S_ + q0 + w * 32 + mi * 16 + lo) * NH_ + h) * HD_;
#pragma unroll
      for (int ks = 0; ks < 4; ks++)
        qf[mi][ks] = *reinterpret_cast<const bf16x8_t*>(q + qbase + ks * 32 + hi * 8);
    }

    f32x4_t o_acc[2][8] = {};
    f32x4_t l_acc[2] = {};
    float m_prev[2][4];
#pragma unroll
    for (int mi = 0; mi < 2; mi++)
#pragma unroll
      for (int r = 0; r < 4; r++) m_prev[mi][r] = -1e30f;

    const int nkt = qt * 2 + 2;

    // prefetch tile 0 into regs
#pragma unroll
    for (int i = 0; i < 4; i++) {
      kreg[i] = *reinterpret_cast<const bf16x8_t*>(kvb + (size_t)kkey[i] * 2048 + khc[i] * 8);
      vreg[i] = *reinterpret_cast<const bf16x8_t*>(kvb + (size_t)vkey[i] * 2048 + 1024 + vhc[i] * 8);
    }

    for (int kt = 0; kt < nkt; kt++) {
      const int kt0 = kt * 64;
      __syncthreads();  // previous iter's LDS consumers done
      // write staged regs -> LDS
#pragma unroll
      for (int i = 0; i < 4; i++)
        *reinterpret_cast<bf16x8_t*>(&Ks[kkey[i] * 132 + khc[i] * 8]) = kreg[i];
#pragma unroll
      for (int i = 0; i < 4; i++)
#pragma unroll
        for (int e = 0; e < 8; e++) Vt[(vhc[i] * 8 + e) * 68 + vkey[i]] = vreg[i][e];
      __syncthreads();
      // prefetch next tile (issued BEFORE compute; waitcnt lands at next iter's write)
      if (kt + 1 < nkt) {
        const int nt0 = (kt + 1) * 64;
#pragma unroll
        for (int i = 0; i < 4; i++) {
          kreg[i] = *reinterpret_cast<const bf16x8_t*>(kvb + (size_t)(nt0 + kkey[i]) * 2048 + khc[i] * 8);
          vreg[i] = *reinterpret_cast<const bf16x8_t*>(kvb + (size_t)(nt0 + vkey[i]) * 2048 + 1024 + vhc[i] * 8);
        }
      }

      // S = Q K^T
      f32x4_t s_acc[2][4] = {};
      __builtin_amdgcn_s_setprio(1);
#pragma unroll
      for (int ks = 0; ks < 4; ks++) {
        bf16x8_t kf[4];
#pragma unroll
        for (int t = 0; t < 4; t++)
          kf[t] = *reinterpret_cast<const bf16x8_t*>(&Ks[(t * 16 + lo) * 132 + ks * 32 + hi * 8]);
#pragma unroll
        for (int mi = 0; mi < 2; mi++)
#pragma unroll
          for (int t = 0; t < 4; t++)
            s_acc[mi][t] = __builtin_amdgcn_mfma_f32_16x16x32_bf16(qf[mi][ks], kf[t], s_acc[mi][t], 0, 0, 0);
      }
      __builtin_amdgcn_s_setprio(0);

#pragma unroll
      for (int mi = 0; mi < 2; mi++) {
        const int rowbase = q0 + w * 32 + mi * 16;
        // mask needed iff max key (kt0+63) exceeds min row (rowbase)
        const bool need_mask = (kt0 + 63) > rowbase;  // wave-uniform
        float sv[4][4];
#pragma unroll
        for (int t = 0; t < 4; t++)
#pragma unroll
          for (int r = 0; r < 4; r++) {
            float val = s_acc[mi][t][r] * SC;
            if (need_mask && (kt0 + t * 16 + lo) > (rowbase + hi * 4 + r)) val = -1e30f;
            sv[t][r] = val;
          }
        float alpha[4], mnew[4];
#pragma unroll
        for (int r = 0; r < 4; r++) {
          float mx = fmaxf(fmaxf(sv[0][r], sv[1][r]), fmaxf(sv[2][r], sv[3][r]));
#pragma unroll
          for (int off = 1; off < 16; off <<= 1) mx = fmaxf(mx, __shfl_xor(mx, off));
          mnew[r] = fmaxf(m_prev[mi][r], mx);
          alpha[r] = __builtin_amdgcn_exp2f(m_prev[mi][r] - mnew[r]);
          m_prev[mi][r] = mnew[r];
        }
#pragma unroll
        for (int t = 0; t < 4; t++)
#pragma unroll
          for (int r = 0; r < 4; r++)
            Ps[w][(mi * 16 + hi * 4 + r) * 68 + t * 16 + lo] =
                (__bf16)__builtin_amdgcn_exp2f(sv[t][r] - mnew[r]);
#pragma unroll
        for (int t8 = 0; t8 < 8; t8++)
#pragma unroll
          for (int r = 0; r < 4; r++) o_acc[mi][t8][r] *= alpha[r];
#pragma unroll
        for (int r = 0; r < 4; r++) l_acc[mi][r] *= alpha[r];
      }

      // O += P V ; l += P . 1   (in-wave LDS write->read, compiler orders lgkmcnt)
      __builtin_amdgcn_s_setprio(1);
#pragma unroll
      for (int ks2 = 0; ks2 < 2; ks2++) {
        bf16x8_t pf[2];
#pragma unroll
        for (int mi = 0; mi < 2; mi++)
          pf[mi] = *reinterpret_cast<const bf16x8_t*>(&Ps[w][(mi * 16 + lo) * 68 + ks2 * 32 + hi * 8]);
#pragma unroll
        for (int mi = 0; mi < 2; mi++)
          l_acc[mi] = __builtin_amdgcn_mfma_f32_16x16x32_bf16(pf[mi], ones, l_acc[mi], 0, 0, 0);
#pragma unroll
        for (int t8 = 0; t8 < 8; t8++) {
          bf16x8_t vf = *reinterpret_cast<const bf16x8_t*>(&Vt[(t8 * 16 + lo) * 68 + ks2 * 32 + hi * 8]);
#pragma unroll
          for (int mi = 0; mi < 2; mi++)
            o_acc[mi][t8] = __builtin_amdgcn_mfma_f32_16x16x32_bf16(pf[mi], vf, o_acc[mi][t8], 0, 0, 0);
        }
      }
      __builtin_amdgcn_s_setprio(0);
    }

    // epilogue for this pass
#pragma unroll
    for (int mi = 0; mi < 2; mi++)
#pragma unroll
      for (int r = 0; r < 4; r++) {
        const float inv = 1.0f / l_acc[mi][r];
        const int qr = q0 + w * 32 + mi * 16 + hi * 4 + r;
        const size_t obase = ((size_t)(b * S_ + qr) * NH_ + h) * HD_;
#pragma unroll
        for (int t8 = 0; t8 < 8; t8++)
          o[obase + t8 * 16 + lo] = (__bf16)(o_acc[mi][t8][r] * inv);
      }
  }
}

extern "C" void kernel_launch(void* const* d_in, const int* in_sizes, int n_in,
                              void* d_out, int out_size, void* d_ws, size_t ws_size,
                              hipStream_t stream) {
  const float* x = (const float*)d_in[0];
  const float* wq = (const float*)d_in[1];
  const float* wk = (const float*)d_in[2];
  const float* wv = (const float*)d_in[3];
  const float* wo = (const float*)d_in[4];
  const float* fcos = (const float*)d_in[5];
  const float* fsin = (const float*)d_in[6];
  float* out = (float*)d_out;

  // ws layout (bytes): [0,32M) xb then wob ; [32M,80M) wqkv then ab@[32M,64M)
  //                    [80M,112M) qb ; [112M,128M) kvb.  Peak 128 MiB.
  __bf16* xb   = (__bf16*)d_ws;                              // 16.7M elts
  __bf16* wqkv = xb + (size_t)16777216;                      // 25.2M elts (wq|wk|wv rows)
  __bf16* qb   = (__bf16*)d_ws + (size_t)41943040;           // (M,NH,HD) 16.7M
  __bf16* kvb  = qb + (size_t)16777216;                      // (M,2048): K|V per row, 8.4M
  __bf16* wob  = xb;                                         // reuses xb after QKV GEMM
  __bf16* ab   = wqkv;                                       // reuses wqkv after QKV GEMM

  convert_main<<<20480, 256, 0, stream>>>(x, wq, wk, wv, xb, wqkv);
  gemm_bt<true, false><<<dim3(48, 32), 256, 0, stream>>>(xb, wqkv, qb, kvb, 6144, D_);
  convert_wo<<<8192, 256, 0, stream>>>(wo, wob);
  rope_kernel<<<(M_ * (NH_ + NKV_) * (HD_ / 2)) / 256, 256, 0, stream>>>(qb, kvb, fcos, fsin);
  attn_kernel<<<dim3(8, NH_, B_), 256, 0, stream>>>(qb, kvb, ab);
  gemm_bt<false, true><<<dim3(32, 32), 256, 0, stream>>>(ab, wob, out, nullptr, D_, D_);
}

// Round 3
// 894.529 us; speedup vs baseline: 1.2350x; 1.1081x over previous
//
#include <hip/hip_runtime.h>
#include <hip/hip_bf16.h>

#define B_ 2
#define S_ 2048
#define D_ 4096
#define NH_ 32
#define NKV_ 8
#define HD_ 128
#define M_ (B_ * S_)

typedef __bf16 bf16x8_t __attribute__((ext_vector_type(8)));
typedef __bf16 bf16x4_t __attribute__((ext_vector_type(4)));
typedef __bf16 bf16x2_t __attribute__((ext_vector_type(2)));
typedef float f32x4_t __attribute__((ext_vector_type(4)));
typedef short short4_t __attribute__((ext_vector_type(4)));

__device__ __forceinline__ void gload16(const __bf16* g, __bf16* l) {
  __builtin_amdgcn_global_load_lds(
      (const __attribute__((address_space(1))) void*)g,
      (__attribute__((address_space(3))) void*)l, 16, 0, 0);
}

// 16x16x16 bf16 MFMA (legacy shape, gfx950 ISA §10). B-fragment k-layout
// (k = (lane>>4)*4 + r) matches the swapped-QK D-layout exactly -> P never
// leaves registers.
#if __has_builtin(__builtin_amdgcn_mfma_f32_16x16x16bf16_1k)
__device__ __forceinline__ f32x4_t mfma16(bf16x4_t a, bf16x4_t b, f32x4_t c) {
  return __builtin_amdgcn_mfma_f32_16x16x16bf16_1k(
      __builtin_bit_cast(short4_t, a), __builtin_bit_cast(short4_t, b), c, 0, 0, 0);
}
#else
// Fallback: D tied to C ("+v") so the accumulator chains in-place; s_nop
// padding covers the MFMA->VALU read hazard the compiler won't insert for asm.
__device__ __forceinline__ f32x4_t mfma16(bf16x4_t a, bf16x4_t b, f32x4_t c) {
  asm("v_mfma_f32_16x16x16_bf16 %0, %1, %2, %0\n\ts_nop 7\n\ts_nop 7"
      : "+v"(c) : "v"(a), "v"(b));
  return c;
}
#endif

// ---------------- fp32 -> bf16 converts ----------------
__global__ __launch_bounds__(256) void convert_main(const float* __restrict__ x,
                                                    const float* __restrict__ wq,
                                                    const float* __restrict__ wk,
                                                    const float* __restrict__ wv,
                                                    __bf16* __restrict__ xb,
                                                    __bf16* __restrict__ wqkv) {
  size_t c = (size_t)blockIdx.x * 256 + threadIdx.x;
  const float* src;
  __bf16* dst;
  if (c < 2097152) { src = x + c * 8; dst = xb + c * 8; }
  else if (c < 4194304) { c -= 2097152; src = wq + c * 8; dst = wqkv + c * 8; }
  else if (c < 4718592) { c -= 4194304; src = wk + c * 8; dst = wqkv + 16777216 + c * 8; }
  else { c -= 4718592; src = wv + c * 8; dst = wqkv + 20971520 + c * 8; }
  const float4* s4 = reinterpret_cast<const float4*>(src);
  float4 a = s4[0], b = s4[1];
  bf16x8_t t;
  t[0] = (__bf16)a.x; t[1] = (__bf16)a.y; t[2] = (__bf16)a.z; t[3] = (__bf16)a.w;
  t[4] = (__bf16)b.x; t[5] = (__bf16)b.y; t[6] = (__bf16)b.z; t[7] = (__bf16)b.w;
  *reinterpret_cast<bf16x8_t*>(dst) = t;
}

__global__ __launch_bounds__(256) void convert_wo(const float* __restrict__ wo,
                                                  __bf16* __restrict__ wob) {
  size_t c = (size_t)blockIdx.x * 256 + threadIdx.x;
  const float4* s4 = reinterpret_cast<const float4*>(wo + c * 8);
  float4 a = s4[0], b = s4[1];
  bf16x8_t t;
  t[0] = (__bf16)a.x; t[1] = (__bf16)a.y; t[2] = (__bf16)a.z; t[3] = (__bf16)a.w;
  t[4] = (__bf16)b.x; t[5] = (__bf16)b.y; t[6] = (__bf16)b.z; t[7] = (__bf16)b.w;
  *reinterpret_cast<bf16x8_t*>(wob + c * 8) = t;
}

// ---------------- GEMM (m97 structure): C = A[M][K] * Bm[N][K]^T ----------------
// SPLIT epilogue: n0<4096 -> Q (ldc 4096); 4096..5120 -> K-only cache (ldc 1024);
// >=5120 -> V written TRANSPOSED to vtg[(b*1024+chan)][s] (8B bf16x4 stores,
// 4 consecutive s per store) so attention can stage V^T with vector LDS writes.
template <bool SPLIT, bool OUTF32>
__global__ __launch_bounds__(256) void gemm_bt(const __bf16* __restrict__ A,
                                               const __bf16* __restrict__ Bm,
                                               void* __restrict__ C0,
                                               void* __restrict__ C1,
                                               void* __restrict__ C2,
                                               int N, int K) {
  __shared__ __attribute__((aligned(16))) __bf16 As[128 * 32];  // unpadded: global_load_lds order
  __shared__ __attribute__((aligned(16))) __bf16 Bs[128 * 32];
  const int tid = threadIdx.x;
  const int lane = tid & 63;
  const int w = tid >> 6;
  const int lo = lane & 15;
  const int hi = lane >> 4;
  const int wm = (w & 1) * 64;
  const int wn = (w >> 1) * 64;
  const int m0 = blockIdx.y * 128;
  const int n0 = blockIdx.x * 128;

  const int srow = w * 32 + (lane >> 2);
  const int scol = (lane & 3) * 8;
  const __bf16* ga0 = A + (size_t)(m0 + srow) * K + scol;
  const __bf16* ga1 = A + (size_t)(m0 + srow + 16) * K + scol;
  const __bf16* gb0 = Bm + (size_t)(n0 + srow) * K + scol;
  const __bf16* gb1 = Bm + (size_t)(n0 + srow + 16) * K + scol;
  __bf16* la0 = &As[(w * 32) * 32];
  __bf16* la1 = &As[(w * 32 + 16) * 32];
  __bf16* lb0 = &Bs[(w * 32) * 32];
  __bf16* lb1 = &Bs[(w * 32 + 16) * 32];

  f32x4_t acc[4][4] = {};

  for (int k0 = 0; k0 < K; k0 += 32) {
    __syncthreads();
    gload16(ga0 + k0, la0);
    gload16(ga1 + k0, la1);
    gload16(gb0 + k0, lb0);
    gload16(gb1 + k0, lb1);
    __syncthreads();  // drains vmcnt before barrier -> LDS valid
    bf16x8_t af[4], bfr[4];
#pragma unroll
    for (int mi = 0; mi < 4; mi++)
      af[mi] = *reinterpret_cast<const bf16x8_t*>(&As[(wm + mi * 16 + lo) * 32 + hi * 8]);
#pragma unroll
    for (int ni = 0; ni < 4; ni++)
      bfr[ni] = *reinterpret_cast<const bf16x8_t*>(&Bs[(wn + ni * 16 + lo) * 32 + hi * 8]);
#pragma unroll
    for (int mi = 0; mi < 4; mi++)
#pragma unroll
      for (int ni = 0; ni < 4; ni++)
        acc[mi][ni] = __builtin_amdgcn_mfma_f32_16x16x32_bf16(af[mi], bfr[ni], acc[mi][ni], 0, 0, 0);
  }

  // epilogue: D layout col=lane&15, row=(lane>>4)*4+r
  if constexpr (SPLIT) {
    if (n0 >= 5120) {
      // V path: write transposed. chan = v-channel (hkv*128+hd), s = token.
      __bf16* vtg = (__bf16*)C2;
#pragma unroll
      for (int mi = 0; mi < 4; mi++) {
        const int mrow = m0 + wm + mi * 16 + hi * 4;
        const int bidx = mrow >> 11;
        const int s0 = mrow & 2047;
#pragma unroll
        for (int ni = 0; ni < 4; ni++) {
          const int chan = (n0 - 5120) + wn + ni * 16 + lo;
          bf16x4_t v4;
#pragma unroll
          for (int r = 0; r < 4; r++) v4[r] = (__bf16)acc[mi][ni][r];
          *reinterpret_cast<bf16x4_t*>(vtg + ((size_t)(bidx * 1024 + chan)) * 2048 + s0) = v4;
        }
      }
      return;
    }
  }
  __bf16* Cb = nullptr;
  float* Cf = nullptr;
  int ldc, nb;
  if constexpr (SPLIT) {
    if (n0 < 4096) { Cb = (__bf16*)C0; ldc = 4096; nb = n0; }
    else { Cb = (__bf16*)C1; ldc = 1024; nb = n0 - 4096; }
  } else {
    ldc = N; nb = n0;
    if constexpr (OUTF32) Cf = (float*)C0; else Cb = (__bf16*)C0;
  }
#pragma unroll
  for (int mi = 0; mi < 4; mi++) {
    const int mrow = m0 + wm + mi * 16 + hi * 4;
#pragma unroll
    for (int ni = 0; ni < 4; ni++) {
      const int ncol = nb + wn + ni * 16 + lo;
#pragma unroll
      for (int r = 0; r < 4; r++) {
        if constexpr (OUTF32)
          Cf[(size_t)(mrow + r) * ldc + ncol] = acc[mi][ni][r];
        else
          Cb[(size_t)(mrow + r) * ldc + ncol] = (__bf16)acc[mi][ni][r];
      }
    }
  }
}

// ---------------- RoPE (in-place; q: (M,NH,HD), k: (M,1024) K-only) ----------------
__global__ __launch_bounds__(256) void rope_kernel(__bf16* __restrict__ q,
                                                   __bf16* __restrict__ k,
                                                   const float* __restrict__ fcos,
                                                   const float* __restrict__ fsin) {
  const int p = blockIdx.x * 256 + threadIdx.x;
  const int j = p & 63;
  int rem = p >> 6;
  const int hh = rem % (NH_ + NKV_);
  rem /= (NH_ + NKV_);
  const int s = rem % S_;
  const int b = rem / S_;
  const float c = fcos[s * 64 + j];
  const float sn = fsin[s * 64 + j];
  __bf16* base;
  if (hh < NH_)
    base = q + ((size_t)(b * S_ + s) * NH_ + hh) * HD_ + 2 * j;
  else
    base = k + (size_t)(b * S_ + s) * 1024 + (hh - NH_) * HD_ + 2 * j;
  bf16x2_t xv = *reinterpret_cast<const bf16x2_t*>(base);
  const float xe = (float)xv[0], xo = (float)xv[1];
  bf16x2_t ov;
  ov[0] = (__bf16)(xe * c - xo * sn);
  ov[1] = (__bf16)(xe * sn + xo * c);
  *reinterpret_cast<bf16x2_t*>(base) = ov;
}

// ---------------- Flash attention (swapped-operand, P stays in registers) ----
// vs R1 (312 us, MfmaUtil 10%, ~136 DS ops/thread-iter):
//  - QK^T computed SWAPPED: mfma(K_frag, Q_frag) -> S^T; each lane holds 16
//    scores for ONE q-row (q = lane&15). Row-max = local tree + 2 shfl_xor
//    (was 32 shfl); m/l/alpha are lane scalars; l-reduce deferred to epilogue.
//  - PV computed as O^T = V^T P^T via mfma_f32_16x16x16_bf16: its B-fragment
//    layout (k = hi*4+r) IS the swapped-QK D-layout -> P never touches LDS
//    (Ps buffer + 36 DS ops/thread-iter deleted).
//  - V arrives PRE-TRANSPOSED from the QKV GEMM (vtg[b][chan][s]) -> V staging
//    is 4 ds_write_b128 (was 32 scalar ds_write_b16).
//  - keeps pairing, XCD pinning, one-ahead reg prefetch, setprio.
__global__ __launch_bounds__(256) void attn_kernel(const __bf16* __restrict__ q,
                                                   const __bf16* __restrict__ k,
                                                   const __bf16* __restrict__ vt,
                                                   __bf16* __restrict__ o) {
  const int flat = blockIdx.x + (blockIdx.y << 3) + (blockIdx.z << 8);
  const int hkv = flat & 7;               // pin KV head-group to one XCD
  const int idx = flat >> 3;
  const int h = hkv * 4 + ((idx >> 3) & 3);
  const int b = idx >> 5;
  const int xpair = idx & 7;              // pairs (xpair, 15-xpair)

  const int tid = threadIdx.x;
  const int lane = tid & 63;
  const int w = tid >> 6;
  const int lo = lane & 15;
  const int hi = lane >> 4;

  __shared__ __attribute__((aligned(16))) __bf16 Ks[64 * 132];  // [key][hd] pad 128->132
  __shared__ __attribute__((aligned(16))) __bf16 Vs[128 * 68];  // [hd][key] pad 64->68

  constexpr float SC = 0.08838834764831845f * 1.44269504088896f;  // scale * log2(e)

  const __bf16* kbase = k + (size_t)b * S_ * 1024 + hkv * 128;
  const __bf16* vbase = vt + ((size_t)(b * 1024 + hkv * 128)) * 2048;
  int kkey[4], khc[4], vhd[4], vkc[4];
#pragma unroll
  for (int i = 0; i < 4; i++) {
    const int c = tid + i * 256;
    kkey[i] = c >> 4; khc[i] = c & 15;   // K: [64 keys][16 chunks of 8]
    vhd[i] = c >> 3; vkc[i] = c & 7;     // V^T: [128 hd][8 chunks of 8 keys]
  }

  bf16x8_t kreg[4], vreg[4];

  for (int pass = 0; pass < 2; pass++) {
    const int qt = pass ? (15 - xpair) : xpair;
    const int q0 = qt * 128;

    // Q fragments (B-operand of swapped QK)
    bf16x8_t qf[2][4];
#pragma unroll
    for (int mi = 0; mi < 2; mi++) {
      const size_t qbase = ((size_t)(b * S_ + q0 + w * 32 + mi * 16 + lo) * NH_ + h) * HD_;
#pragma unroll
      for (int ks = 0; ks < 4; ks++)
        qf[mi][ks] = *reinterpret_cast<const bf16x8_t*>(q + qbase + ks * 32 + hi * 8);
    }

    // O^T accumulator: lane holds q = mi*16+lo, hd = t8*16 + hi*4 + r
    f32x4_t o_acc[2][8] = {};
    float l_part[2] = {0.f, 0.f};
    float m_prev[2] = {-1e30f, -1e30f};

    const int nkt = qt * 2 + 2;

    // prefetch tile 0 into regs
#pragma unroll
    for (int i = 0; i < 4; i++) {
      kreg[i] = *reinterpret_cast<const bf16x8_t*>(kbase + (size_t)kkey[i] * 1024 + khc[i] * 8);
      vreg[i] = *reinterpret_cast<const bf16x8_t*>(vbase + (size_t)vhd[i] * 2048 + vkc[i] * 8);
    }

    for (int kt = 0; kt < nkt; kt++) {
      const int kt0 = kt * 64;
      __syncthreads();  // previous iter's LDS consumers done
#pragma unroll
      for (int i = 0; i < 4; i++) {
        *reinterpret_cast<bf16x8_t*>(&Ks[kkey[i] * 132 + khc[i] * 8]) = kreg[i];
        *reinterpret_cast<bf16x8_t*>(&Vs[vhd[i] * 68 + vkc[i] * 8]) = vreg[i];
      }
      __syncthreads();
      if (kt + 1 < nkt) {
        const int nt0 = kt0 + 64;
#pragma unroll
        for (int i = 0; i < 4; i++) {
          kreg[i] = *reinterpret_cast<const bf16x8_t*>(kbase + (size_t)(nt0 + kkey[i]) * 1024 + khc[i] * 8);
          vreg[i] = *reinterpret_cast<const bf16x8_t*>(vbase + (size_t)vhd[i] * 2048 + nt0 + vkc[i] * 8);
        }
      }

      // S^T: s2[t][mi][r] = S[q = q0+w*32+mi*16+lo][key = kt0 + t*16 + hi*4 + r]
      f32x4_t s2[4][2] = {};
      __builtin_amdgcn_s_setprio(1);
#pragma unroll
      for (int ks = 0; ks < 4; ks++) {
        bf16x8_t kf[4];
#pragma unroll
        for (int t = 0; t < 4; t++)
          kf[t] = *reinterpret_cast<const bf16x8_t*>(&Ks[(t * 16 + lo) * 132 + ks * 32 + hi * 8]);
#pragma unroll
        for (int t = 0; t < 4; t++)
#pragma unroll
          for (int mi = 0; mi < 2; mi++)
            s2[t][mi] = __builtin_amdgcn_mfma_f32_16x16x32_bf16(kf[t], qf[mi][ks], s2[t][mi], 0, 0, 0);
      }
      __builtin_amdgcn_s_setprio(0);

      // online softmax, fully lane-local except 2 shfl for the row-max
      bf16x4_t pb[2][4];
#pragma unroll
      for (int mi = 0; mi < 2; mi++) {
        const int qrow = q0 + w * 32 + mi * 16 + lo;
        const bool need_mask = (kt0 + 63) > (q0 + w * 32 + mi * 16);  // wave-uniform
        float sv[4][4];
#pragma unroll
        for (int t = 0; t < 4; t++)
#pragma unroll
          for (int r = 0; r < 4; r++) {
            float val = s2[t][mi][r] * SC;
            if (need_mask && (kt0 + t * 16 + hi * 4 + r) > qrow) val = -1e30f;
            sv[t][r] = val;
          }
        float mx = sv[0][0];
#pragma unroll
        for (int t = 0; t < 4; t++)
#pragma unroll
          for (int r = 0; r < 4; r++) mx = fmaxf(mx, sv[t][r]);
        mx = fmaxf(mx, __shfl_xor(mx, 16));
        mx = fmaxf(mx, __shfl_xor(mx, 32));
        const float mnew = fmaxf(m_prev[mi], mx);
        const float alpha = __builtin_amdgcn_exp2f(m_prev[mi] - mnew);
        m_prev[mi] = mnew;
        float psum = 0.f;
#pragma unroll
        for (int t = 0; t < 4; t++)
#pragma unroll
          for (int r = 0; r < 4; r++) {
            const float p = __builtin_amdgcn_exp2f(sv[t][r] - mnew);
            psum += p;
            pb[mi][t][r] = (__bf16)p;
          }
        l_part[mi] = l_part[mi] * alpha + psum;  // partial over this lane's 16 keys
#pragma unroll
        for (int t8 = 0; t8 < 8; t8++) o_acc[mi][t8] *= alpha;
      }

      // O^T += V^T P^T  (16x16x16; A = Vs rows, B = pb straight from registers)
      __builtin_amdgcn_s_setprio(1);
#pragma unroll
      for (int t = 0; t < 4; t++) {
#pragma unroll
        for (int t8 = 0; t8 < 8; t8++) {
          bf16x4_t va = *reinterpret_cast<const bf16x4_t*>(&Vs[(t8 * 16 + lo) * 68 + t * 16 + hi * 4]);
#pragma unroll
          for (int mi = 0; mi < 2; mi++)
            o_acc[mi][t8] = mfma16(va, pb[mi][t], o_acc[mi][t8]);
        }
      }
      __builtin_amdgcn_s_setprio(0);
    }

    // epilogue: reduce l across the 4 lanes of each q-group, normalize, store
#pragma unroll
    for (int mi = 0; mi < 2; mi++) {
      float l = l_part[mi];
      l += __shfl_xor(l, 16);
      l += __shfl_xor(l, 32);
      const float inv = 1.0f / l;
      const int qr = q0 + w * 32 + mi * 16 + lo;
      const size_t obase = ((size_t)(b * S_ + qr) * NH_ + h) * HD_ + hi * 4;
#pragma unroll
      for (int t8 = 0; t8 < 8; t8++) {
        bf16x4_t ov;
#pragma unroll
        for (int r = 0; r < 4; r++) ov[r] = (__bf16)(o_acc[mi][t8][r] * inv);
        *reinterpret_cast<bf16x4_t*>(o + obase + t8 * 16) = ov;
      }
    }
  }
}

extern "C" void kernel_launch(void* const* d_in, const int* in_sizes, int n_in,
                              void* d_out, int out_size, void* d_ws, size_t ws_size,
                              hipStream_t stream) {
  const float* x = (const float*)d_in[0];
  const float* wq = (const float*)d_in[1];
  const float* wk = (const float*)d_in[2];
  const float* wv = (const float*)d_in[3];
  const float* wo = (const float*)d_in[4];
  const float* fcos = (const float*)d_in[5];
  const float* fsin = (const float*)d_in[6];
  float* out = (float*)d_out;

  // ws layout (elts): [0,16.7M) xb/wob ; [16.7M,41.9M) wqkv then ab ;
  // [41.9M,58.7M) qb ; [58.7M,62.9M) kvb (K-only, M x 1024) ;
  // [62.9M,67.1M) vtg (V^T, (B*1024) x 2048).  Peak 128 MiB.
  __bf16* xb   = (__bf16*)d_ws;
  __bf16* wqkv = xb + (size_t)16777216;
  __bf16* qb   = (__bf16*)d_ws + (size_t)41943040;
  __bf16* kvb  = qb + (size_t)16777216;     // 4.2M elts
  __bf16* vtg  = kvb + (size_t)4194304;     // 4.2M elts
  __bf16* wob  = xb;                        // reuses xb after QKV GEMM
  __bf16* ab   = wqkv;                      // reuses wqkv after QKV GEMM

  convert_main<<<20480, 256, 0, stream>>>(x, wq, wk, wv, xb, wqkv);
  gemm_bt<true, false><<<dim3(48, 32), 256, 0, stream>>>(xb, wqkv, qb, kvb, vtg, 6144, D_);
  convert_wo<<<8192, 256, 0, stream>>>(wo, wob);
  rope_kernel<<<(M_ * (NH_ + NKV_) * (HD_ / 2)) / 256, 256, 0, stream>>>(qb, kvb, fcos, fsin);
  attn_kernel<<<dim3(8, NH_, B_), 256, 0, stream>>>(qb, kvb, vtg, ab);
  gemm_bt<false, true><<<dim3(32, 32), 256, 0, stream>>>(ab, wob, out, nullptr, nullptr, D_, D_);
}